// Round 6
// baseline (116.379 us; speedup 1.0000x reference)
//
#include <hip/hip_runtime.h>

#define B_N 32
#define LQ  1024
#define LK  1024
#define DH  128

typedef __attribute__((ext_vector_type(4))) float    f32x4;
typedef __attribute__((ext_vector_type(8))) short    s16x8;
typedef __attribute__((ext_vector_type(4))) _Float16 f16x4;
typedef __attribute__((ext_vector_type(8))) _Float16 f16x8;

// fp32 -> bf16 round-to-nearest-even
__device__ inline unsigned short f2bf(float f) {
    union { float f; unsigned u; } c; c.f = f;
    unsigned u = c.u;
    u += 0x7fffu + ((u >> 16) & 1u);
    return (unsigned short)(u >> 16);
}

// logit2 = score * (1/sqrt(128)) * log2(e)
#define ESCALE 0.12751743f

// async global->LDS, 16B per lane (dest must be wave-uniform base + lane*16)
#define G2L16(gp, lp) __builtin_amdgcn_global_load_lds(                         \
    (const __attribute__((address_space(1))) void*)(gp),                        \
    (__attribute__((address_space(3))) void*)(lp), 16, 0, 0)

// ---------------------------------------------------------------------------
// Prepass (compute blocks byte-identical to r5). Grid is 2049: block 2048
// builds the LPT unit list for attn (r6 change).
// blocks 0..1023: K tiles -> Kb bf16 fragments for QK^T (16x16x32).
// blocks 1024..2047: V tiles -> Vt f16 fragment-PAIRS for PV (16x16x16).
// block 2048: rank batches by nch DESC (32-lane shuffle rank, no scratch),
//   emit UL[1024]: unit u = batch | (q32 << 5), rank-major -> blocks with
//   the most chunks get the smallest blockIdx -> dispatched first (LPT).
// ---------------------------------------------------------------------------
__global__ __launch_bounds__(256)
void prep_kv(const float* __restrict__ K, const float* __restrict__ V,
             const int* __restrict__ VL,
             unsigned short* __restrict__ Kb, _Float16* __restrict__ Vt,
             int* __restrict__ UL)
{
    __shared__ float tl[32 * 132];
    __shared__ int rank_sh[32];
    const int tid  = threadIdx.x;
    const int lane = tid & 63;
    const int wv   = tid >> 6;
    const int n    = lane & 15;
    const int quad = lane >> 4;

    const int idx = blockIdx.x;

    if (idx == 2048) {
        // ---- LPT schedule builder ----
        if (tid < 64) {
            int my = 0;
            if (lane < 32) {
                const int v = VL[lane];
                my = (v > 0) ? ((v + 63) >> 6) : 16;
            }
            int rank = 0;
            #pragma unroll
            for (int k = 0; k < 32; ++k) {
                const int other = __shfl(my, k);
                if (lane < 32 && (other > my || (other == my && k < lane))) ++rank;
            }
            if (lane < 32) rank_sh[rank] = lane;   // bijective: rank -> batch
        }
        __syncthreads();
        for (int u = tid; u < 1024; u += 256) {
            const int r = u >> 5, q = u & 31;
            UL[u] = rank_sh[r] | (q << 5);
        }
        return;
    }

    const bool isK = (idx >> 10) == 0;
    const int  b   = (idx & 7) | (((idx >> 3) & 3) << 3);
    const int  kt  = (idx >> 5) & 31;

    const int vl = VL[b];
    if (isK) {
        if (vl <= 0 || kt >= 2 * ((vl + 63) >> 6)) return;   // block-uniform
    } else {
        const int nch = (vl > 0) ? ((vl + 63) >> 6) : 16;
        if (kt >= 2 * nch) return;                           // block-uniform
    }

    const float4* src = (const float4*)((isK ? K : V) + ((size_t)b * LK + kt * 32) * DH);
    #pragma unroll
    for (int h = 0; h < 4; ++h) {
        const int i2 = h * 256 + tid;
        const int row = i2 >> 5, c4 = i2 & 31;
        *(float4*)&tl[row * 132 + c4 * 4] = src[i2];
    }
    __syncthreads();

    if (isK) {
        union { s16x8 v; unsigned short u[8]; } t8;
        #pragma unroll
        for (int h = 0; h < 2; ++h) {
            const int f = wv * 2 + h;
            const int tt2 = f >> 2, s = f & 3;
            const float* p = &tl[(tt2 * 16 + n) * 132 + s * 32 + quad * 8];
            const float4 a = *(const float4*)p;
            const float4 c = *(const float4*)(p + 4);
            t8.u[0] = f2bf(a.x); t8.u[1] = f2bf(a.y); t8.u[2] = f2bf(a.z); t8.u[3] = f2bf(a.w);
            t8.u[4] = f2bf(c.x); t8.u[5] = f2bf(c.y); t8.u[6] = f2bf(c.z); t8.u[7] = f2bf(c.w);
            const int w = b * 256 + (kt * 2 + tt2) * 4 + s;
            *(s16x8*)(Kb + (size_t)w * 512 + lane * 8) = t8.v;
        }
    } else {
        #pragma unroll
        for (int h = 0; h < 2; ++h) {
            const int f  = wv * 2 + h;
            const int kg = f >> 2, dp = f & 3;
            f16x8 t8;
            #pragma unroll
            for (int i = 0; i < 4; ++i) {
                const float* row = &tl[(kg * 16 + quad * 4 + i) * 132 + dp * 32 + n];
                t8[i]     = (_Float16)row[0];
                t8[4 + i] = (_Float16)row[16];
            }
            const int v = (b * 64 + kt * 2 + kg) * 4 + dp;
            *(f16x8*)(Vt + (size_t)v * 512 + lane * 8) = t8;
        }
    }
}

// ---------------------------------------------------------------------------
// Attention v6: LPT-scheduled 32-row units (the round-6 change).
// r5 post-mortem: attn pinned at ~30us across all structures while mean
// work is ~17 chunk-slots/CU -> makespan = max_CU(2-sample nch sum) ~ 30.
// With 512 blocks on exactly 512 slots there is NO dispatch queue; every
// slot's load is a random 2-sample sum (tail ~32). v6: 1024 units x 32
// q-rows -> 2 units/slot; block i runs UL[i] (built by prep, nch-descending)
// -> HW in-order dispatch = LPT greedy: big batches first, stragglers
// backfill freed slots. Inside a unit all 4 waves stay active every chunk:
// wave (h = wv>>1, j = wv&1) computes qtile h over kpos-half j (g = j*2+g2)
// -> per-wave per-chunk work halves; split-K merge over j at the end
// through bufK/bufV (free after the loop; r0/r1's proven additive fixed-max
// merge). STAGE + depth-2 counted-vmcnt pipeline byte-identical to r5.
// Numerics: partial sums over kpos-halves then one add — same split-K
// structure that passed r0/r1 at the same absmax.
// LDS 64KB -> 2 blocks/CU, 8 waves/CU. Register rule: never index a
// register array with a runtime value (g is address-only; pA indexed by
// compile-time g2). XCD batch-affinity swizzle dropped (r3 proved null;
// dynamic assignment precludes it anyway).
// Transposed-S trick unchanged: S^T = K.Q^T C-layout == A-operand layout
// of 16x16x16 f16 MFMA -> exp2(S^T) feeds PV directly.
// ---------------------------------------------------------------------------
__global__ __launch_bounds__(256)
void attn_fwd(const float* __restrict__ Q, const unsigned short* __restrict__ Kb,
              const _Float16* __restrict__ Vt, const int* __restrict__ VL,
              const int* __restrict__ UL, float* __restrict__ O)
{
    __shared__ __align__(16) unsigned short bufK[2][16 * 512];  // 16 KB / buf
    __shared__ __align__(16) _Float16       bufV[2][16 * 512];  // 16 KB / buf

    const int tid  = threadIdx.x;
    const int lane = tid & 63;
    const int wv   = tid >> 6;
    const int h    = wv >> 1;      // qtile within the 32-row unit
    const int j    = wv & 1;       // kpos-half of each chunk
    const int quad = lane >> 4;
    const int m16  = lane & 15;

    const int uv = UL[blockIdx.x];
    const int b  = uv & 31;
    const int q0 = (uv >> 5) * 32;

    const int vl  = VL[b];
    const int nch = (vl > 0) ? ((vl + 63) >> 6) : 16;
    const float emaskval = (vl == 0) ? 1.0f : 0.0f;

    // Q fragments for this wave's qtile (B-operand of transposed QK^T)
    s16x8 qf[4];
    {
        const float* qrow = Q + ((size_t)b * LQ + q0 + h * 16 + m16) * DH + quad * 8;
        #pragma unroll
        for (int s = 0; s < 4; ++s) {
            const float4 a = *(const float4*)(qrow + s * 32);
            const float4 c = *(const float4*)(qrow + s * 32 + 4);
            union { s16x8 v; unsigned short u[8]; } t;
            t.u[0] = f2bf(a.x); t.u[1] = f2bf(a.y); t.u[2] = f2bf(a.z); t.u[3] = f2bf(a.w);
            t.u[4] = f2bf(c.x); t.u[5] = f2bf(c.y); t.u[6] = f2bf(c.z); t.u[7] = f2bf(c.w);
            qf[s] = t.v;
        }
    }

    f32x4 o[8];
    #pragma unroll
    for (int dt = 0; dt < 8; ++dt) o[dt] = (f32x4){0.f, 0.f, 0.f, 0.f};
    float lrun = 0.f;

    // chunk t occupies shorts [t*8192, (t+1)*8192) of this batch's Kb / Vt
    const unsigned short* kg0 = Kb + (size_t)b * (256 * 512);
    const _Float16*       vg0 = Vt + (size_t)b * (256 * 512);
    const int co = tid * 8;  // this thread's 16B slot within a 16KB chunk copy

    // STAGE(c, t): 8 x global_load_lds dwordx4 per thread (4 K + 4 V)
    //              = 8 vmcnt events per wave
#define STAGE(c, t)                                                             \
    do {                                                                        \
        const unsigned short* gk_ = kg0 + (size_t)(t) * 8192;                   \
        const _Float16*       gv_ = vg0 + (size_t)(t) * 8192;                   \
        _Pragma("unroll")                                                       \
        for (int it_ = 0; it_ < 4; ++it_)                                       \
            G2L16(gk_ + it_ * 2048 + co, &bufK[c][it_ * 2048 + co]);            \
        _Pragma("unroll")                                                       \
        for (int it_ = 0; it_ < 4; ++it_)                                       \
            G2L16(gv_ + it_ * 2048 + co, &bufV[c][it_ * 2048 + co]);            \
    } while (0)

    // prologue: stage chunks 0 and 1 (chunk 1 is always within the batch's
    // 16-chunk allocation; unused/poison bytes are never computed if nch==1)
    STAGE(0, 0);
    STAGE(1, 1);

    for (int t = 0; t < nch; ++t) {
        // wait for chunk t to land: only chunk t+1's 8 per-wave loads may
        // remain in flight. Last iteration: drain everything.
        if (t + 1 < nch) { asm volatile("s_waitcnt vmcnt(8)" ::: "memory"); }
        else             { asm volatile("s_waitcnt vmcnt(0)" ::: "memory"); }
        __builtin_amdgcn_sched_barrier(0);
        __builtin_amdgcn_s_barrier();          // (a) chunk t visible to all waves
        __builtin_amdgcn_sched_barrier(0);

        const unsigned short* bk = &bufK[t & 1][0];
        const _Float16*       bv = &bufV[t & 1][0];
        const bool maskc = (t * 64 + 64 > vl);
        f16x4 pA[2];

        // ---- S^T = K Q^T over this wave's kpos-half (g = j*2+g2) ----
        #pragma unroll
        for (int g2 = 0; g2 < 2; ++g2) {
            const int g = j * 2 + g2;
            f32x4 st = (f32x4){0.f, 0.f, 0.f, 0.f};
            #pragma unroll
            for (int s = 0; s < 4; ++s) {
                const s16x8 kf = *(const s16x8*)(bk + (g * 4 + s) * 512 + lane * 8);
                st = __builtin_amdgcn_mfma_f32_16x16x32_bf16(kf, qf[s], st, 0, 0, 0);
            }
            #pragma unroll
            for (int i = 0; i < 4; ++i) {
                float e = __builtin_amdgcn_exp2f(st[i] * ESCALE);
                if (maskc && (t * 64 + g * 16 + quad * 4 + i >= vl)) e = emaskval;
                lrun += e;
                pA[g2][i] = (_Float16)e;
            }
        }

        // ---- O += P V over this wave's kpos-half ----
        #pragma unroll
        for (int g2 = 0; g2 < 2; ++g2) {
            const int g = j * 2 + g2;
            #pragma unroll
            for (int dp = 0; dp < 4; ++dp) {
                const f16x8 w8 = *(const f16x8*)(bv + (g * 4 + dp) * 512 + lane * 8);
                const f16x4 lo = __builtin_shufflevector(w8, w8, 0, 1, 2, 3);
                const f16x4 hi = __builtin_shufflevector(w8, w8, 4, 5, 6, 7);
                o[dp * 2]     = __builtin_amdgcn_mfma_f32_16x16x16f16(pA[g2], lo, o[dp * 2],     0, 0, 0);
                o[dp * 2 + 1] = __builtin_amdgcn_mfma_f32_16x16x16f16(pA[g2], hi, o[dp * 2 + 1], 0, 0, 0);
            }
        }

        __builtin_amdgcn_s_barrier();          // (b) all waves done reading buf[t&1]
        __builtin_amdgcn_sched_barrier(0);
        if (t + 2 < nch) STAGE(t & 1, t + 2);  // overwrite the vacated buffer
    }
#undef STAGE

    // ---- split-K merge over j per qtile h; bufK/bufV are free now
    //      (all reads done past barrier (b) of the last iter, DMA drained) ----
    f32x4* Om = (f32x4*)&bufK[0][0];   // [2 qtiles][8 dt][64 lanes]
    float*  Lm = (float*)&bufV[0][0];  // [2 qtiles][64 lanes]
    if (j == 1) {
        #pragma unroll
        for (int dt = 0; dt < 8; ++dt) Om[(h * 8 + dt) * 64 + lane] = o[dt];
        Lm[h * 64 + lane] = lrun;
    }
    __syncthreads();
    if (j == 0) {
        f32x4 om[8];
        #pragma unroll
        for (int dt = 0; dt < 8; ++dt) om[dt] = o[dt] + Om[(h * 8 + dt) * 64 + lane];
        float L = lrun + Lm[h * 64 + lane];

        // L[qrow=m16] total across quads, then per-row 1/L via shfl
        L += __shfl_xor(L, 16);
        L += __shfl_xor(L, 32);
        const size_t obase = ((size_t)b * LQ + q0 + h * 16 + quad * 4) * DH + m16;
        #pragma unroll
        for (int r = 0; r < 4; ++r) {
            const float inv = 1.0f / __shfl(L, quad * 4 + r);
            #pragma unroll
            for (int dt = 0; dt < 8; ++dt)
                O[obase + (size_t)r * DH + dt * 16] = om[dt][r] * inv;
        }
    }
}

extern "C" void kernel_launch(void* const* d_in, const int* in_sizes, int n_in,
                              void* d_out, int out_size, void* d_ws, size_t ws_size,
                              hipStream_t stream) {
    const float* Q  = (const float*)d_in[0];
    const float* K  = (const float*)d_in[1];
    const float* V  = (const float*)d_in[2];
    const int*   VL = (const int*)d_in[3];
    float* O = (float*)d_out;
    (void)in_sizes; (void)n_in; (void)out_size; (void)ws_size;

    unsigned short* Kb = (unsigned short*)d_ws;                      // 8 MB K fragments
    _Float16*       Vt = (_Float16*)(Kb + (size_t)B_N * 256 * 512);  // 8 MB V frag-pairs
    int*            UL = (int*)(Vt + (size_t)B_N * 256 * 512);       // 4 KB LPT unit list

    prep_kv<<<dim3(2049), dim3(256), 0, stream>>>(K, V, VL, Kb, Vt, UL);
    attn_fwd<<<dim3(1024), dim3(256), 0, stream>>>(Q, Kb, Vt, VL, UL, O);
}

// Round 7
// 114.628 us; speedup vs baseline: 1.0153x; 1.0153x over previous
//
#include <hip/hip_runtime.h>

#define B_N 32
#define LQ  1024
#define LK  1024
#define DH  128

typedef __attribute__((ext_vector_type(4))) float    f32x4;
typedef __attribute__((ext_vector_type(8))) short    s16x8;
typedef __attribute__((ext_vector_type(4))) _Float16 f16x4;
typedef __attribute__((ext_vector_type(8))) _Float16 f16x8;

// fp32 -> bf16 round-to-nearest-even
__device__ inline unsigned short f2bf(float f) {
    union { float f; unsigned u; } c; c.f = f;
    unsigned u = c.u;
    u += 0x7fffu + ((u >> 16) & 1u);
    return (unsigned short)(u >> 16);
}

// logit2 = score * (1/sqrt(128)) * log2(e)
#define ESCALE 0.12751743f

// async global->LDS, 16B per lane (dest must be wave-uniform base + lane*16)
#define G2L16(gp, lp) __builtin_amdgcn_global_load_lds(                         \
    (const __attribute__((address_space(1))) void*)(gp),                        \
    (__attribute__((address_space(3))) void*)(lp), 16, 0, 0)

// ---------------------------------------------------------------------------
// Prepass (compute blocks byte-identical to r5). Grid 2049: block 2048
// builds the PAIRED unit list for attn (r7 change).
// blocks 0..1023: K tiles -> Kb bf16 fragments for QK^T (16x16x32).
// blocks 1024..2047: V tiles -> Vt f16 fragment-PAIRS for PV (16x16x16).
// block 2048: rank batches by nch DESC (32-lane shuffle rank), expand to
//   512 sorted units (rank r, qg q -> sorted[r*16+q]), then PAIR:
//   UL[i] = sorted[i] (i<256), UL[i+256] = sorted[511-i]. In-order
//   round-robin dispatch co-locates blocks i and i+256 on one CU (the
//   stride-256 family) -> each CU gets one heavy + one light unit ->
//   per-CU work ~ nch_max+nch_min ~ uniform. r6 post-mortem: LPT via
//   1024x32-row units DOUBLED staging DMA + barriers (balance win eaten);
//   pairing gets the balance at zero traffic cost.
// ---------------------------------------------------------------------------
__global__ __launch_bounds__(256)
void prep_kv(const float* __restrict__ K, const float* __restrict__ V,
             const int* __restrict__ VL,
             unsigned short* __restrict__ Kb, _Float16* __restrict__ Vt,
             int* __restrict__ UL)
{
    __shared__ float tl[32 * 132];
    __shared__ int rank_sh[32];
    const int tid  = threadIdx.x;
    const int lane = tid & 63;
    const int wv   = tid >> 6;
    const int n    = lane & 15;
    const int quad = lane >> 4;

    const int idx = blockIdx.x;

    if (idx == 2048) {
        // ---- paired-balance schedule builder ----
        if (tid < 64) {
            int my = 0;
            if (lane < 32) {
                const int v = VL[lane];
                my = (v > 0) ? ((v + 63) >> 6) : 16;
            }
            int rank = 0;
            #pragma unroll
            for (int k = 0; k < 32; ++k) {
                const int other = __shfl(my, k);
                if (lane < 32 && (other > my || (other == my && k < lane))) ++rank;
            }
            if (lane < 32) rank_sh[rank] = lane;   // bijective: rank -> batch
        }
        __syncthreads();
        for (int i = tid; i < 512; i += 256) {
            const int s = (i < 256) ? i : (511 - (i - 256));  // sorted unit id
            const int r = s >> 4, q = s & 15;
            UL[i] = rank_sh[r] | (q << 5);
        }
        return;
    }

    const bool isK = (idx >> 10) == 0;
    const int  b   = (idx & 7) | (((idx >> 3) & 3) << 3);
    const int  kt  = (idx >> 5) & 31;

    const int vl = VL[b];
    if (isK) {
        if (vl <= 0 || kt >= 2 * ((vl + 63) >> 6)) return;   // block-uniform
    } else {
        const int nch = (vl > 0) ? ((vl + 63) >> 6) : 16;
        if (kt >= 2 * nch) return;                           // block-uniform
    }

    const float4* src = (const float4*)((isK ? K : V) + ((size_t)b * LK + kt * 32) * DH);
    #pragma unroll
    for (int h = 0; h < 4; ++h) {
        const int i2 = h * 256 + tid;
        const int row = i2 >> 5, c4 = i2 & 31;
        *(float4*)&tl[row * 132 + c4 * 4] = src[i2];
    }
    __syncthreads();

    if (isK) {
        union { s16x8 v; unsigned short u[8]; } t8;
        #pragma unroll
        for (int h = 0; h < 2; ++h) {
            const int f = wv * 2 + h;
            const int tt2 = f >> 2, s = f & 3;
            const float* p = &tl[(tt2 * 16 + n) * 132 + s * 32 + quad * 8];
            const float4 a = *(const float4*)p;
            const float4 c = *(const float4*)(p + 4);
            t8.u[0] = f2bf(a.x); t8.u[1] = f2bf(a.y); t8.u[2] = f2bf(a.z); t8.u[3] = f2bf(a.w);
            t8.u[4] = f2bf(c.x); t8.u[5] = f2bf(c.y); t8.u[6] = f2bf(c.z); t8.u[7] = f2bf(c.w);
            const int w = b * 256 + (kt * 2 + tt2) * 4 + s;
            *(s16x8*)(Kb + (size_t)w * 512 + lane * 8) = t8.v;
        }
    } else {
        #pragma unroll
        for (int h = 0; h < 2; ++h) {
            const int f  = wv * 2 + h;
            const int kg = f >> 2, dp = f & 3;
            f16x8 t8;
            #pragma unroll
            for (int i = 0; i < 4; ++i) {
                const float* row = &tl[(kg * 16 + quad * 4 + i) * 132 + dp * 32 + n];
                t8[i]     = (_Float16)row[0];
                t8[4 + i] = (_Float16)row[16];
            }
            const int v = (b * 64 + kt * 2 + kg) * 4 + dp;
            *(f16x8*)(Vt + (size_t)v * 512 + lane * 8) = t8;
        }
    }
}

// ---------------------------------------------------------------------------
// Attention v7 = r5's best structure (4 waves x 16 rows, 64-row block,
// depth-2 counted-vmcnt pipeline) + PAIRED unit decode (the only change:
// blockIdx -> UL lookup instead of static swizzle; pure permutation ->
// numerics identical to r5).
// Pipeline (r5, kept): prologue stages chunks 0+1; per iter wait vmcnt(8)
// (chunk t landed, t+1 still flying), barrier (a) = t visible to all
// waves, compute t, barrier (b) = buf[t&1] free, STAGE(t+2) into it.
// LDS 64KB -> 2 blocks/CU, 8 waves/CU. Register rule: never index a
// register array with a runtime value (buf index t&1 is LDS memory, fine).
// Transposed-S trick unchanged: S^T = K.Q^T C-layout == A-operand layout
// of 16x16x16 f16 MFMA -> exp2(S^T) feeds PV directly.
// ---------------------------------------------------------------------------
__global__ __launch_bounds__(256)
void attn_fwd(const float* __restrict__ Q, const unsigned short* __restrict__ Kb,
              const _Float16* __restrict__ Vt, const int* __restrict__ VL,
              const int* __restrict__ UL, float* __restrict__ O)
{
    __shared__ __align__(16) unsigned short bufK[2][16 * 512];  // 16 KB / buf
    __shared__ __align__(16) _Float16       bufV[2][16 * 512];  // 16 KB / buf

    const int tid  = threadIdx.x;
    const int lane = tid & 63;
    const int w    = tid >> 6;     // wave id == qtile id (16 q-rows each)
    const int quad = lane >> 4;
    const int m16  = lane & 15;

    const int uv = UL[blockIdx.x];
    const int b  = uv & 31;
    const int q0 = (uv >> 5) * 64;

    const int vl  = VL[b];
    const int nch = (vl > 0) ? ((vl + 63) >> 6) : 16;
    const float emaskval = (vl == 0) ? 1.0f : 0.0f;

    // Q fragments for this wave's qtile (B-operand of transposed QK^T)
    s16x8 qf[4];
    {
        const float* qrow = Q + ((size_t)b * LQ + q0 + w * 16 + m16) * DH + quad * 8;
        #pragma unroll
        for (int s = 0; s < 4; ++s) {
            const float4 a = *(const float4*)(qrow + s * 32);
            const float4 c = *(const float4*)(qrow + s * 32 + 4);
            union { s16x8 v; unsigned short u[8]; } t;
            t.u[0] = f2bf(a.x); t.u[1] = f2bf(a.y); t.u[2] = f2bf(a.z); t.u[3] = f2bf(a.w);
            t.u[4] = f2bf(c.x); t.u[5] = f2bf(c.y); t.u[6] = f2bf(c.z); t.u[7] = f2bf(c.w);
            qf[s] = t.v;
        }
    }

    f32x4 o[8];
    #pragma unroll
    for (int dt = 0; dt < 8; ++dt) o[dt] = (f32x4){0.f, 0.f, 0.f, 0.f};
    float lrun = 0.f;

    // chunk t occupies shorts [t*8192, (t+1)*8192) of this batch's Kb / Vt
    const unsigned short* kg0 = Kb + (size_t)b * (256 * 512);
    const _Float16*       vg0 = Vt + (size_t)b * (256 * 512);
    const int co = tid * 8;  // this thread's 16B slot within a 16KB chunk copy

    // STAGE(c, t): 8 x global_load_lds dwordx4 per thread (4 K + 4 V)
    //              = 8 vmcnt events per wave
#define STAGE(c, t)                                                             \
    do {                                                                        \
        const unsigned short* gk_ = kg0 + (size_t)(t) * 8192;                   \
        const _Float16*       gv_ = vg0 + (size_t)(t) * 8192;                   \
        _Pragma("unroll")                                                       \
        for (int it_ = 0; it_ < 4; ++it_)                                       \
            G2L16(gk_ + it_ * 2048 + co, &bufK[c][it_ * 2048 + co]);            \
        _Pragma("unroll")                                                       \
        for (int it_ = 0; it_ < 4; ++it_)                                       \
            G2L16(gv_ + it_ * 2048 + co, &bufV[c][it_ * 2048 + co]);            \
    } while (0)

    // prologue: stage chunks 0 and 1 (chunk 1 is always within the batch's
    // 16-chunk allocation; unused/poison bytes are never computed if nch==1)
    STAGE(0, 0);
    STAGE(1, 1);

    for (int t = 0; t < nch; ++t) {
        // wait for chunk t to land: only chunk t+1's 8 per-wave loads may
        // remain in flight. Last iteration: drain everything.
        if (t + 1 < nch) { asm volatile("s_waitcnt vmcnt(8)" ::: "memory"); }
        else             { asm volatile("s_waitcnt vmcnt(0)" ::: "memory"); }
        __builtin_amdgcn_sched_barrier(0);
        __builtin_amdgcn_s_barrier();          // (a) chunk t visible to all waves
        __builtin_amdgcn_sched_barrier(0);

        const unsigned short* bk = &bufK[t & 1][0];
        const _Float16*       bv = &bufV[t & 1][0];
        const bool maskc = (t * 64 + 64 > vl);
        f16x4 pA[4];

        // ---- S^T = K Q^T per 16-kpos tile g, softmaxed immediately ----
        #pragma unroll
        for (int g = 0; g < 4; ++g) {
            f32x4 st = (f32x4){0.f, 0.f, 0.f, 0.f};
            #pragma unroll
            for (int s = 0; s < 4; ++s) {
                const s16x8 kf = *(const s16x8*)(bk + (g * 4 + s) * 512 + lane * 8);
                st = __builtin_amdgcn_mfma_f32_16x16x32_bf16(kf, qf[s], st, 0, 0, 0);
            }
            #pragma unroll
            for (int i = 0; i < 4; ++i) {
                float e = __builtin_amdgcn_exp2f(st[i] * ESCALE);
                if (maskc && (t * 64 + g * 16 + quad * 4 + i >= vl)) e = emaskval;
                lrun += e;
                pA[g][i] = (_Float16)e;
            }
        }

        // ---- O += P V : 4 kpos-tiles x 4 d-pairs ----
        #pragma unroll
        for (int g = 0; g < 4; ++g) {
            #pragma unroll
            for (int dp = 0; dp < 4; ++dp) {
                const f16x8 w8 = *(const f16x8*)(bv + (g * 4 + dp) * 512 + lane * 8);
                const f16x4 lo = __builtin_shufflevector(w8, w8, 0, 1, 2, 3);
                const f16x4 hi = __builtin_shufflevector(w8, w8, 4, 5, 6, 7);
                o[dp * 2]     = __builtin_amdgcn_mfma_f32_16x16x16f16(pA[g], lo, o[dp * 2],     0, 0, 0);
                o[dp * 2 + 1] = __builtin_amdgcn_mfma_f32_16x16x16f16(pA[g], hi, o[dp * 2 + 1], 0, 0, 0);
            }
        }

        __builtin_amdgcn_s_barrier();          // (b) all waves done reading buf[t&1]
        __builtin_amdgcn_sched_barrier(0);
        if (t + 2 < nch) STAGE(t & 1, t + 2);  // overwrite the vacated buffer
    }
#undef STAGE

    // ---- epilogue: no split-K merge; wave owns its 16 rows outright ----
    float L = lrun;
    L += __shfl_xor(L, 16);
    L += __shfl_xor(L, 32);
    const size_t obase = ((size_t)b * LQ + q0 + w * 16 + quad * 4) * DH + m16;
    #pragma unroll
    for (int r = 0; r < 4; ++r) {
        const float inv = 1.0f / __shfl(L, quad * 4 + r);
        #pragma unroll
        for (int dt = 0; dt < 8; ++dt)
            O[obase + (size_t)r * DH + dt * 16] = o[dt][r] * inv;
    }
}

extern "C" void kernel_launch(void* const* d_in, const int* in_sizes, int n_in,
                              void* d_out, int out_size, void* d_ws, size_t ws_size,
                              hipStream_t stream) {
    const float* Q  = (const float*)d_in[0];
    const float* K  = (const float*)d_in[1];
    const float* V  = (const float*)d_in[2];
    const int*   VL = (const int*)d_in[3];
    float* O = (float*)d_out;
    (void)in_sizes; (void)n_in; (void)out_size; (void)ws_size;

    unsigned short* Kb = (unsigned short*)d_ws;                      // 8 MB K fragments
    _Float16*       Vt = (_Float16*)(Kb + (size_t)B_N * 256 * 512);  // 8 MB V frag-pairs
    int*            UL = (int*)(Vt + (size_t)B_N * 256 * 512);       // 2 KB paired unit list

    prep_kv<<<dim3(2049), dim3(256), 0, stream>>>(K, V, VL, Kb, Vt, UL);
    attn_fwd<<<dim3(512), dim3(256), 0, stream>>>(Q, Kb, Vt, VL, UL, O);
}